// Round 5
// baseline (433.653 us; speedup 1.0000x reference)
//
#include <hip/hip_runtime.h>

#define D 128
#define BSH 8          // 256 nodes per bucket
#define CAP 10240      // slots per bucket (mean ~8192, sigma ~90 -> 22 sigma)
#define CH 8192        // edges per k_bin block (512 threads, 391 blocks)
                       // CH=4096 regressed (spans ~42B -> partial-line write amp 6x);
                       // CH=8192 spans ~84B, all CUs covered. [R10/R11 post-mortem]
                       // R12 FAILED: per-edge global fp32 atomics for ow[] cost ~100us
                       // (3.2M x 32B uncacheable RMW at coherence point). binB restored.
                       // R13 WIN: LDS bucket-sort + run-contiguous copy-out in k_bin
                       // (write amp 5x -> ~1.5x), 428 -> 400us.
                       // R14 WIN: agg8 32-bit saddr gathers + csr prefetch + masked
                       // tail, 400 -> 377us (agg8 67.7 -> 56.3us each).
                       // R15 FAILED: dwordx2/16-lane/4-quarter reshape, agg8 80us.
                       // At mean deg 32 the per-node fixed costs (shuffles, stream
                       // setup, tails) dominate when streams shrink to deg/4.
                       // R16: R14 shape restored; single variable = gather batch
                       // depth 8 -> 16 (double outstanding loads, same wave shape).

typedef unsigned short ushort_t;
typedef unsigned int uint_t;
typedef unsigned char uchar_t;

typedef __attribute__((ext_vector_type(8))) short frag_ab;   // 8 bf16 (4 VGPRs)
typedef __attribute__((ext_vector_type(4))) float frag_cd;   // 4 fp32 acc
typedef __attribute__((ext_vector_type(2))) float float2v;

union frag_u { ushort_t u[8]; frag_ab v; };

// Channel permutation: MFMA C-col c = j*16+l16 stored at position p = (c&15)*8 + (c>>4).
// Inverse: c = (p&7)*16 + (p>>3). Elementwise stages use positions; W2 rows and the
// finalize w3 contraction are permuted to match.

__device__ __forceinline__ float bf2f(ushort_t u) {
    union { uint_t i; float f; } v; v.i = ((uint_t)u) << 16; return v.f;
}
__device__ __forceinline__ ushort_t f2bf(float f) {
    union { float f; uint_t i; } v; v.f = f;
    uint_t u = v.i;
    u += 0x7fffu + ((u >> 16) & 1u);   // round-to-nearest-even
    return (ushort_t)(u >> 16);
}

// fp8 accumulate helpers (agg8)
__device__ __forceinline__ void acc_fp8(uint_t w, float2v& aA, float2v& aB) {
    aA += __builtin_amdgcn_cvt_pk_f32_fp8(w, false);
    aB += __builtin_amdgcn_cvt_pk_f32_fp8(w, true);
}
// gather with explicit 32-bit BYTE offset -> compiler emits saddr+voffset form
// (1 v_lshl_add_u32 per gather instead of 64-bit address arith). [R14]
__device__ __forceinline__ uint_t g8(const uint_t* __restrict__ t8, uint_t byteoff) {
    return *(const uint_t*)((const char*)t8 + byteoff);
}

// ---------------- edge binning into 256-node buckets, 4B packed entries ----------
// binA (dst-keyed): (src<<8) | (dst&255).  binB (src-keyed): (dst<<8) | (src&255).
// R13: entries are first bucket-sorted in LDS (local scan + cursor — same proven
// reservation scheme, NOT the R11 global counting sort), then copied out as
// contiguous runs so global writes coalesce into full lines.
__launch_bounds__(512)
__global__ void k_bin(const int* __restrict__ src, const int* __restrict__ dst,
                      int* __restrict__ curA, int* __restrict__ curB,
                      uint_t* __restrict__ binA, uint_t* __restrict__ binB,
                      int E, int nb) {
    __shared__ int hA[512], hB[512], sc[512], gb[512];
    __shared__ ushort_t sbkt[CH];     // bucket id per local slot
    __shared__ uint_t sent[CH];       // packed entry per local slot (bucket-sorted)
    int tx = threadIdx.x;
    hA[tx] = 0; hB[tx] = 0;
    __syncthreads();

    int e0 = blockIdx.x * CH;
    int e1 = min(e0 + CH, E);
    int total = e1 - e0;

    for (int e = e0 + tx; e < e1; e += 512) {
        atomicAdd(&hA[dst[e] >> BSH], 1);
        atomicAdd(&hB[src[e] >> BSH], 1);
    }
    __syncthreads();

    // ================= side A (dst-keyed) =================
    {
        int v = hA[tx];
        sc[tx] = v;
        __syncthreads();
        for (int d = 1; d < 512; d <<= 1) {
            int t = (tx >= d) ? sc[tx - d] : 0;
            __syncthreads();
            sc[tx] += t;
            __syncthreads();
        }
        sc[tx] -= v;                                   // exclusive scan (local base)
        gb[tx] = v ? atomicAdd(&curA[tx], v) : 0;      // global base (bucket-relative)
        hA[tx] = 0;                                    // reuse as local cursor
        __syncthreads();
        for (int e = e0 + tx; e < e1; e += 512) {
            int s = src[e], d = dst[e];
            int k = d >> BSH;
            int pos = sc[k] + atomicAdd(&hA[k], 1);
            sent[pos] = ((uint_t)s << 8) | (uint_t)(d & 255);
            sbkt[pos] = (ushort_t)k;
        }
        __syncthreads();
        for (int p = tx; p < total; p += 512) {        // run-contiguous, coalesced
            int k = sbkt[p];
            int gp = gb[k] + (p - sc[k]);
            if (gp < CAP) binA[(size_t)k * CAP + gp] = sent[p];
        }
        __syncthreads();
    }

    // ================= side B (src-keyed) =================
    {
        int v = hB[tx];
        sc[tx] = v;
        __syncthreads();
        for (int d = 1; d < 512; d <<= 1) {
            int t = (tx >= d) ? sc[tx - d] : 0;
            __syncthreads();
            sc[tx] += t;
            __syncthreads();
        }
        sc[tx] -= v;
        gb[tx] = v ? atomicAdd(&curB[tx], v) : 0;
        hB[tx] = 0;
        __syncthreads();
        for (int e = e0 + tx; e < e1; e += 512) {
            int s = src[e], d = dst[e];
            int k = s >> BSH;
            int pos = sc[k] + atomicAdd(&hB[k], 1);
            sent[pos] = ((uint_t)d << 8) | (uint_t)(s & 255);
            sbkt[pos] = (ushort_t)k;
        }
        __syncthreads();
        for (int p = tx; p < total; p += 512) {
            int k = sbkt[p];
            int gp = gb[k] + (p - sc[k]);
            if (gp < CAP) binB[(size_t)k * CAP + gp] = sent[p];
        }
    }
}

// ---------------- per-bucket: degree + dinv + row ranges + CSR fill ----------------
__launch_bounds__(1024)
__global__ void k_csr(const uint_t* __restrict__ binA, const int* __restrict__ curA,
                      float* __restrict__ dinv, int* __restrict__ row_beg,
                      int* __restrict__ row_end, int* __restrict__ csr_src, int N) {
    __shared__ int hist[256];
    __shared__ int scan[256];
    int b = blockIdx.x;
    int tx = threadIdx.x;
    int cnt = min(curA[b], CAP);
    const uint_t* eb = binA + (size_t)b * CAP;

    if (tx < 256) hist[tx] = 0;
    __syncthreads();
    for (int e = tx; e < cnt; e += 1024)
        atomicAdd(&hist[eb[e] & 255u], 1);
    __syncthreads();
    int v = 0;
    if (tx < 256) { v = hist[tx]; scan[tx] = v; }
    __syncthreads();
    for (int dd = 1; dd < 256; dd <<= 1) {
        int t = 0;
        if (tx < 256 && tx >= dd) t = scan[tx - dd];
        __syncthreads();
        if (tx < 256) scan[tx] += t;
        __syncthreads();
    }
    if (tx < 256) {
        int my_excl = scan[tx] - v;
        int node = b * 256 + tx;
        if (node < N) {
            dinv[node] = rsqrtf((float)(v + 1));        // +1 self-loop
            row_beg[node] = b * CAP + my_excl;
            row_end[node] = b * CAP + my_excl + v;
        }
        hist[tx] = my_excl;                              // reuse as fill cursor
    }
    __syncthreads();
    for (int e = tx; e < cnt; e += 1024) {
        uint_t pk = eb[e];
        int pos = b * CAP + atomicAdd(&hist[pk & 255u], 1);
        csr_src[pos] = (int)(pk >> 8);
    }
}

// ---------------- weight pack + bias permute (one launch) ----------------
__global__ void k_wpack(const float* __restrict__ W1, const float* __restrict__ W2,
                        ushort_t* __restrict__ h1, ushort_t* __restrict__ l1,
                        ushort_t* __restrict__ h2, ushort_t* __restrict__ l2,
                        const float* __restrict__ b1, const float* __restrict__ b2,
                        float* __restrict__ bp1, float* __restrict__ bp2) {
    if (blockIdx.x == 128) {
        int p = threadIdx.x;
        if (p < 128) {
            int c = (p & 7) * 16 + (p >> 3);
            bp1[p] = b1[c];
            bp2[p] = b2[c];
        }
        return;
    }
    int gid = blockIdx.x * 256 + threadIdx.x;      // 0..32767
    int which = gid >> 14;
    int idx = gid & 16383;
    int k = idx >> 7, n = idx & 127;
    float w = which ? W2[(((k & 7) * 16) + (k >> 3)) * 128 + n] : W1[idx];
    ushort_t h = f2bf(w);
    ushort_t l = f2bf(w - bf2f(h));                // residual, makes W effectively fp32
    int c = k >> 5, quad = (k >> 3) & 3, jj = k & 7;
    int j = n >> 4, l16 = n & 15;
    int lane = quad * 16 + l16;
    int dest = ((c * 8 + j) * 64 + lane) * 8 + jj;
    if (which) { h2[dest] = h; l2[dest] = l; }
    else       { h1[dest] = h; l1[dest] = l; }
}

// ---------------- MFMA GEMM, fused scale+fp8 epilogue (permuted, coalesced) -------
template <int IN_F32>
__launch_bounds__(256)
__global__ void gemm_mfma(const void* __restrict__ Av, const ushort_t* __restrict__ Whi,
                          const ushort_t* __restrict__ Wlo, const float* __restrict__ dinv,
                          uchar_t* __restrict__ C8, int nrows) {
    int wave = threadIdx.x >> 6;
    int lane = threadIdx.x & 63;
    int quad = lane >> 4, l16 = lane & 15;
    int base = blockIdx.x * 128 + wave * 32;

    frag_cd acc[2][8];
#pragma unroll
    for (int rt = 0; rt < 2; rt++)
#pragma unroll
        for (int j = 0; j < 8; j++) acc[rt][j] = (frag_cd)0.f;

    const ushort_t* Ab = (const ushort_t*)Av;
    const float* Af = (const float*)Av;

#pragma unroll
    for (int c = 0; c < 4; c++) {
        frag_ab afrag[2];
        int koff = c * 32 + quad * 8;
#pragma unroll
        for (int rt = 0; rt < 2; rt++) {
            int row = min(base + rt * 16 + l16, nrows - 1);
            if (IN_F32) {
                const float* ap = Af + (size_t)row * D + koff;
                float4 a0 = *(const float4*)ap;
                float4 a1 = *(const float4*)(ap + 4);
                frag_u fu;
                fu.u[0] = f2bf(a0.x); fu.u[1] = f2bf(a0.y);
                fu.u[2] = f2bf(a0.z); fu.u[3] = f2bf(a0.w);
                fu.u[4] = f2bf(a1.x); fu.u[5] = f2bf(a1.y);
                fu.u[6] = f2bf(a1.z); fu.u[7] = f2bf(a1.w);
                afrag[rt] = fu.v;
            } else {
                afrag[rt] = *(const frag_ab*)(Ab + (size_t)row * D + koff);
            }
        }
#pragma unroll
        for (int j = 0; j < 8; j++) {
            frag_ab bh = *(const frag_ab*)(Whi + (((c * 8 + j) * 64 + lane) * 8));
            frag_ab bl = *(const frag_ab*)(Wlo + (((c * 8 + j) * 64 + lane) * 8));
#pragma unroll
            for (int rt = 0; rt < 2; rt++) {
                acc[rt][j] = __builtin_amdgcn_mfma_f32_16x16x32_bf16(afrag[rt], bh,
                                                                     acc[rt][j], 0, 0, 0);
                acc[rt][j] = __builtin_amdgcn_mfma_f32_16x16x32_bf16(afrag[rt], bl,
                                                                     acc[rt][j], 0, 0, 0);
            }
        }
    }

#pragma unroll
    for (int rt = 0; rt < 2; rt++) {
        int rbase = base + rt * 16 + quad * 4;
#pragma unroll
        for (int reg = 0; reg < 4; reg++) {
            int row = rbase + reg;
            if (row < nrows) {
                float dv = dinv[row];
                uint_t d0 = (uint_t)__builtin_amdgcn_cvt_pk_fp8_f32(
                    acc[rt][0][reg] * dv, acc[rt][1][reg] * dv, 0, false);
                d0 = (uint_t)__builtin_amdgcn_cvt_pk_fp8_f32(
                    acc[rt][2][reg] * dv, acc[rt][3][reg] * dv, (int)d0, true);
                uint_t d1 = (uint_t)__builtin_amdgcn_cvt_pk_fp8_f32(
                    acc[rt][4][reg] * dv, acc[rt][5][reg] * dv, 0, false);
                d1 = (uint_t)__builtin_amdgcn_cvt_pk_fp8_f32(
                    acc[rt][6][reg] * dv, acc[rt][7][reg] * dv, (int)d1, true);
                uint2 o; o.x = d0; o.y = d1;
                *(uint2*)(C8 + (size_t)row * D + l16 * 8) = o;
            }
        }
    }
}

// ---------------- aggregation (pre-scaled fp8 gather, pure sum, bf16 out) ----------
// out[n][p] = relu?( dn * ( u[n][p] + sum_e u[src][p] ) + bias[p] )
// one wave per node; half-wave 0 takes first ceil(deg/2) edges, half 1 the rest.
// R14 shape (32 lanes/row, dword gathers, 2 halves, 4 shuffles) — R15's quarter
// split regressed (per-node fixed costs dominate at mean deg 32).
// R16: gather batch depth 8 -> 16 (16 outstanding dword gathers per half-wave).
__launch_bounds__(256)
__global__ void agg8(const uint_t* __restrict__ t8, const int* __restrict__ csr_src,
                     const int* __restrict__ row_beg, const int* __restrict__ row_end,
                     const float* __restrict__ dinv, const float* __restrict__ bias,
                     uint_t* __restrict__ out, int n, int do_relu) {
    int node = blockIdx.x * 4 + (threadIdx.x >> 6);
    if (node >= n) return;
    int lane = threadIdx.x & 63;
    int eh = lane >> 5;
    uint_t cl = (uint_t)(lane & 31);
    uint_t cl4 = cl * 4u;

    int beg = row_beg[node];
    int deg = row_end[node] - beg;
    float dn = dinv[node];

    float2v accA = {0.f, 0.f}, accB = {0.f, 0.f};

    if (eh == 0) {   // self term: table already holds dinv[n]*t[n]
        uint_t w = g8(t8, (uint_t)node * 128u + cl4);
        accA = __builtin_amdgcn_cvt_pk_f32_fp8(w, false);
        accB = __builtin_amdgcn_cvt_pk_f32_fp8(w, true);
    }

    int h0 = (deg + 1) >> 1;
    int e    = beg + (eh ? h0 : 0);
    int eend = beg + (eh ? deg : h0);
    int cnt  = eend - e;
    int nfull = cnt >> 4;
    int tail  = cnt & 15;

    uint4 sa, sb, sc_, sd;
    if (cnt > 0) {
        // 4B-aligned 16B loads; may read up to 60B past eend — lands in the
        // adjacent workspace buffers, values clamped/masked below.
        __builtin_memcpy(&sa,  csr_src + e,      16);
        __builtin_memcpy(&sb,  csr_src + e + 4,  16);
        __builtin_memcpy(&sc_, csr_src + e + 8,  16);
        __builtin_memcpy(&sd,  csr_src + e + 12, 16);
    }
    for (int it = 0; it < nfull; ++it) {
        uint4 ca = sa, cb = sb, cc = sc_, cd = sd;
        e += 16;
        if (e < eend) {                     // prefetch next batch's indices early
            __builtin_memcpy(&sa,  csr_src + e,      16);
            __builtin_memcpy(&sb,  csr_src + e + 4,  16);
            __builtin_memcpy(&sc_, csr_src + e + 8,  16);
            __builtin_memcpy(&sd,  csr_src + e + 12, 16);
        }
        uint_t w0  = g8(t8, ca.x * 128u + cl4);
        uint_t w1  = g8(t8, ca.y * 128u + cl4);
        uint_t w2  = g8(t8, ca.z * 128u + cl4);
        uint_t w3  = g8(t8, ca.w * 128u + cl4);
        uint_t w4  = g8(t8, cb.x * 128u + cl4);
        uint_t w5  = g8(t8, cb.y * 128u + cl4);
        uint_t w6  = g8(t8, cb.z * 128u + cl4);
        uint_t w7  = g8(t8, cb.w * 128u + cl4);
        uint_t w8  = g8(t8, cc.x * 128u + cl4);
        uint_t w9  = g8(t8, cc.y * 128u + cl4);
        uint_t w10 = g8(t8, cc.z * 128u + cl4);
        uint_t w11 = g8(t8, cc.w * 128u + cl4);
        uint_t w12 = g8(t8, cd.x * 128u + cl4);
        uint_t w13 = g8(t8, cd.y * 128u + cl4);
        uint_t w14 = g8(t8, cd.z * 128u + cl4);
        uint_t w15 = g8(t8, cd.w * 128u + cl4);
        acc_fp8(w0,  accA, accB);
        acc_fp8(w1,  accA, accB);
        acc_fp8(w2,  accA, accB);
        acc_fp8(w3,  accA, accB);
        acc_fp8(w4,  accA, accB);
        acc_fp8(w5,  accA, accB);
        acc_fp8(w6,  accA, accB);
        acc_fp8(w7,  accA, accB);
        acc_fp8(w8,  accA, accB);
        acc_fp8(w9,  accA, accB);
        acc_fp8(w10, accA, accB);
        acc_fp8(w11, accA, accB);
        acc_fp8(w12, accA, accB);
        acc_fp8(w13, accA, accB);
        acc_fp8(w14, accA, accB);
        acc_fp8(w15, accA, accB);
    }
    if (tail) {
        // sa..sd hold the tail batch (+ garbage beyond). Clamp indices (garbage
        // mostly clamps to n-1 -> hot cached row), mask contributions by position.
        uint_t nm1 = (uint_t)(n - 1);
        uint_t w0  = g8(t8, min(sa.x, nm1) * 128u + cl4);
        uint_t w1  = g8(t8, min(sa.y, nm1) * 128u + cl4);
        uint_t w2  = g8(t8, min(sa.z, nm1) * 128u + cl4);
        uint_t w3  = g8(t8, min(sa.w, nm1) * 128u + cl4);
        uint_t w4  = g8(t8, min(sb.x, nm1) * 128u + cl4);
        uint_t w5  = g8(t8, min(sb.y, nm1) * 128u + cl4);
        uint_t w6  = g8(t8, min(sb.z, nm1) * 128u + cl4);
        uint_t w7  = g8(t8, min(sb.w, nm1) * 128u + cl4);
        uint_t w8  = g8(t8, min(sc_.x, nm1) * 128u + cl4);
        uint_t w9  = g8(t8, min(sc_.y, nm1) * 128u + cl4);
        uint_t w10 = g8(t8, min(sc_.z, nm1) * 128u + cl4);
        uint_t w11 = g8(t8, min(sc_.w, nm1) * 128u + cl4);
        uint_t w12 = g8(t8, min(sd.x, nm1) * 128u + cl4);
        uint_t w13 = g8(t8, min(sd.y, nm1) * 128u + cl4);
        uint_t w14 = g8(t8, min(sd.z, nm1) * 128u + cl4);
        acc_fp8(w0, accA, accB);
        if (tail >  1) acc_fp8(w1,  accA, accB);
        if (tail >  2) acc_fp8(w2,  accA, accB);
        if (tail >  3) acc_fp8(w3,  accA, accB);
        if (tail >  4) acc_fp8(w4,  accA, accB);
        if (tail >  5) acc_fp8(w5,  accA, accB);
        if (tail >  6) acc_fp8(w6,  accA, accB);
        if (tail >  7) acc_fp8(w7,  accA, accB);
        if (tail >  8) acc_fp8(w8,  accA, accB);
        if (tail >  9) acc_fp8(w9,  accA, accB);
        if (tail > 10) acc_fp8(w10, accA, accB);
        if (tail > 11) acc_fp8(w11, accA, accB);
        if (tail > 12) acc_fp8(w12, accA, accB);
        if (tail > 13) acc_fp8(w13, accA, accB);
        if (tail > 14) acc_fp8(w14, accA, accB);
    }

    float a0 = accA.x, a1 = accA.y, a2 = accB.x, a3 = accB.y;
    a0 += __shfl(a0, lane ^ 32, 64);
    a1 += __shfl(a1, lane ^ 32, 64);
    a2 += __shfl(a2, lane ^ 32, 64);
    a3 += __shfl(a3, lane ^ 32, 64);

    if (eh == 0) {
        float4 bb = ((const float4*)bias)[cl];
        float o0 = dn * a0 + bb.x;
        float o1 = dn * a1 + bb.y;
        float o2 = dn * a2 + bb.z;
        float o3 = dn * a3 + bb.w;
        if (do_relu) {
            o0 = fmaxf(o0, 0.f); o1 = fmaxf(o1, 0.f);
            o2 = fmaxf(o2, 0.f); o3 = fmaxf(o3, 0.f);
        }
        uint2 ow;
        ow.x = (uint_t)f2bf(o0) | ((uint_t)f2bf(o1) << 16);
        ow.y = (uint_t)f2bf(o2) | ((uint_t)f2bf(o3) << 16);
        ((uint2*)out)[(size_t)node * 32 + cl] = ow;
    }
}

// ---------------- fused ow + weighted reduce (one block per 256-node bucket) -------
__launch_bounds__(512)
__global__ void wreduce(const ushort_t* __restrict__ h, const uint_t* __restrict__ binB,
                        const int* __restrict__ curB, const float* __restrict__ dinv,
                        float* __restrict__ v, int n) {
    __shared__ float owacc[256];
    __shared__ float s[512];
    int b = blockIdx.x;
    int tx = threadIdx.x;
    if (tx < 256) owacc[tx] = 0.f;
    __syncthreads();
    int cnt = min(curB[b], CAP);
    const uint_t* eb = binB + (size_t)b * CAP;
    for (int e = tx; e < cnt; e += 512) {
        uint_t pk = eb[e];
        atomicAdd(&owacc[pk & 255u], dinv[pk >> 8]);
    }
    __syncthreads();

    int c = tx & 127;
    int rg = tx >> 7;                    // 0..3
    int base = b * 256;
    int lim = min(base + 256, n);
    float acc = 0.f;
    for (int r = base + rg; r < lim; r += 4) {
        float dv = dinv[r];
        float cv = dv * (dv + owacc[r - base]);
        acc += cv * bf2f(h[(size_t)r * D + c]);
    }
    s[tx] = acc;
    __syncthreads();
    if (tx < 128)
        atomicAdd(&v[c], (s[tx] + s[tx + 128]) + (s[tx + 256] + s[tx + 384]));
}

// ---------------- finalize: out[j] = (v @ w3)[j]/N + b3[j], v is permuted ----------
__global__ void finalize(const float* __restrict__ v, const float* __restrict__ w3,
                         const float* __restrict__ b3, float* __restrict__ out, float invn) {
    __shared__ float sv[D];
    int j = threadIdx.x;
    sv[j] = v[j];
    __syncthreads();
    float acc = 0.f;
    for (int k = 0; k < D; k++) {
        int p = (k & 15) * 8 + (k >> 4);    // position of original channel k
        acc += sv[p] * w3[(size_t)k * D + j];
    }
    out[j] = acc * invn + b3[j];
}

extern "C" void kernel_launch(void* const* d_in, const int* in_sizes, int n_in,
                              void* d_out, int out_size, void* d_ws, size_t ws_size,
                              hipStream_t stream) {
    const float* x   = (const float*)d_in[0];
    const int*   ei  = (const int*)d_in[1];
    const float* w1  = (const float*)d_in[2];
    const float* b1  = (const float*)d_in[3];
    const float* w2  = (const float*)d_in[4];
    const float* b2  = (const float*)d_in[5];
    const float* w3  = (const float*)d_in[6];
    const float* b3  = (const float*)d_in[7];
    float* out = (float*)d_out;

    const int N = in_sizes[0] / D;       // 100000
    const int E = in_sizes[1] / 2;       // 3200000
    const int* src = ei;
    const int* dst = ei + E;
    const int nb = (N + 255) >> 8;       // 391 buckets of 256 nodes

    // ---- workspace layout ----
    char* p = (char*)d_ws;
    auto alloc = [&](size_t bytes) -> char* {
        char* r = p;
        p += (bytes + 255) & ~(size_t)255;
        return r;
    };
    char*     zbeg     = p;
    int*      curA     = (int*)alloc(512 * 4);
    int*      curB     = (int*)alloc(512 * 4);
    float*    v        = (float*)alloc((size_t)D * 4);
    char*     zend     = p;
    float*    dinv     = (float*)alloc((size_t)N * 4);
    int*      row_beg  = (int*)alloc((size_t)N * 4);
    int*      row_end  = (int*)alloc((size_t)N * 4);
    ushort_t* wp1h     = (ushort_t*)alloc(16384 * 2);
    ushort_t* wp1l     = (ushort_t*)alloc(16384 * 2);
    ushort_t* wp2h     = (ushort_t*)alloc(16384 * 2);
    ushort_t* wp2l     = (ushort_t*)alloc(16384 * 2);
    float*    bp1      = (float*)alloc(D * 4);
    float*    bp2      = (float*)alloc(D * 4);
    uint_t*   binA     = (uint_t*)alloc((size_t)nb * CAP * 4);  // 16 MB
    uint_t*   binB     = (uint_t*)alloc((size_t)nb * CAP * 4);  // 16 MB
    int*      csr_src  = (int*)alloc((size_t)nb * CAP * 4);     // 16 MB
    ushort_t* bufH     = (ushort_t*)alloc((size_t)N * D * 2);   // bf16 agg out
    uint_t*   buf8     = (uint_t*)alloc((size_t)N * 32 * 4);    // fp8 gather table
    (void)ws_size;

    const int gG = (N + 127) / 128;      // MFMA gemm grid

    // zero curA/curB/v
    hipMemsetAsync(zbeg, 0, (size_t)(zend - zbeg), stream);

    // weight packing + bias permute (single launch, independent of graph work)
    k_wpack<<<129, 256, 0, stream>>>(w1, w2, wp1h, wp1l, wp2h, wp2l, b1, b2, bp1, bp2);

    // graph preprocessing: bin edges (4B entries), then per-bucket degree/CSR
    k_bin<<<(E + CH - 1) / CH, 512, 0, stream>>>(src, dst, curA, curB, binA, binB, E, nb);
    k_csr<<<nb, 1024, 0, stream>>>(binA, curA, dinv, row_beg, row_end, csr_src, N);

    // layer 1: u1 = fp8(dinv * (x@w1)) permuted ; h1 = relu(dn*(sum u1)+b1) (bf16)
    gemm_mfma<1><<<gG, 256, 0, stream>>>(x, wp1h, wp1l, dinv, (uchar_t*)buf8, N);
    agg8<<<(N + 3) / 4, 256, 0, stream>>>(buf8, csr_src, row_beg, row_end, dinv, bp1,
                                          (uint_t*)bufH, N, 1);
    // layer 2 (A permuted, W2 rows permuted to match)
    gemm_mfma<0><<<gG, 256, 0, stream>>>(bufH, wp2h, wp2l, dinv, (uchar_t*)buf8, N);
    agg8<<<(N + 3) / 4, 256, 0, stream>>>(buf8, csr_src, row_beg, row_end, dinv, bp2,
                                          (uint_t*)bufH, N, 1);
    // layer 3 collapsed: v = sum_i cvec[i]*h2[i] (ow fused in) ; out = v@w3/N + b3
    wreduce<<<nb, 512, 0, stream>>>(bufH, binB, curB, dinv, v, N);
    finalize<<<1, D, 0, stream>>>(v, w3, b3, out, 1.0f / (float)N);
}

// Round 6
// 377.662 us; speedup vs baseline: 1.1483x; 1.1483x over previous
//
#include <hip/hip_runtime.h>

#define D 128
#define BSH 8          // 256 nodes per bucket
#define CAP 12288      // slots per bucket (R17: raised from 10240 for CSR padding;
                       // padded bucket total mean ~10.1K, sigma ~116 -> 18 sigma)
#define CH 8192        // edges per k_bin block (512 threads, 391 blocks)
                       // CH=4096 regressed (spans ~42B -> partial-line write amp 6x);
                       // CH=8192 spans ~84B, all CUs covered. [R10/R11 post-mortem]
                       // R12 FAILED: per-edge global fp32 atomics for ow[] ~100us.
                       // R13 WIN: LDS bucket-sort + coalesced copy-out, 428 -> 400us.
                       // R14 WIN: agg8 saddr gathers + csr prefetch + masked tail,
                       // 400 -> 377us (agg8 56.3us each).
                       // R15 FAILED (80us): quarter-wave split; per-node fixed costs
                       // dominate at mean deg 32 — don't shrink stream grain.
                       // R16 FAILED (87us): depth 16; VGPR 52 + 20 VMEM in flight
                       // crossed a resource cliff (occ 71->37%) + heavier tail.
                       // R17: CSR segments padded to x16 with sentinel row N (zero
                       // row in fp8 table) -> agg8 has NO tail/clamps/divergence.

typedef unsigned short ushort_t;
typedef unsigned int uint_t;
typedef unsigned char uchar_t;

typedef __attribute__((ext_vector_type(8))) short frag_ab;   // 8 bf16 (4 VGPRs)
typedef __attribute__((ext_vector_type(4))) float frag_cd;   // 4 fp32 acc
typedef __attribute__((ext_vector_type(2))) float float2v;

union frag_u { ushort_t u[8]; frag_ab v; };

// Channel permutation: MFMA C-col c = j*16+l16 stored at position p = (c&15)*8 + (c>>4).
// Inverse: c = (p&7)*16 + (p>>3). Elementwise stages use positions; W2 rows and the
// finalize w3 contraction are permuted to match.

__device__ __forceinline__ float bf2f(ushort_t u) {
    union { uint_t i; float f; } v; v.i = ((uint_t)u) << 16; return v.f;
}
__device__ __forceinline__ ushort_t f2bf(float f) {
    union { float f; uint_t i; } v; v.f = f;
    uint_t u = v.i;
    u += 0x7fffu + ((u >> 16) & 1u);   // round-to-nearest-even
    return (ushort_t)(u >> 16);
}

// fp8 accumulate helpers (agg8)
__device__ __forceinline__ void acc_fp8(uint_t w, float2v& aA, float2v& aB) {
    aA += __builtin_amdgcn_cvt_pk_f32_fp8(w, false);
    aB += __builtin_amdgcn_cvt_pk_f32_fp8(w, true);
}
// gather with explicit 32-bit BYTE offset -> compiler emits saddr+voffset form
// (1 v_lshl_add_u32 per gather instead of 64-bit address arith). [R14]
__device__ __forceinline__ uint_t g8(const uint_t* __restrict__ t8, uint_t byteoff) {
    return *(const uint_t*)((const char*)t8 + byteoff);
}

// ---------------- edge binning into 256-node buckets, 4B packed entries ----------
// binA (dst-keyed): (src<<8) | (dst&255).  binB (src-keyed): (dst<<8) | (src&255).
// R13: entries are first bucket-sorted in LDS (local scan + cursor), then copied
// out as contiguous runs so global writes coalesce into full lines.
__launch_bounds__(512)
__global__ void k_bin(const int* __restrict__ src, const int* __restrict__ dst,
                      int* __restrict__ curA, int* __restrict__ curB,
                      uint_t* __restrict__ binA, uint_t* __restrict__ binB,
                      int E, int nb) {
    __shared__ int hA[512], hB[512], sc[512], gb[512];
    __shared__ ushort_t sbkt[CH];     // bucket id per local slot
    __shared__ uint_t sent[CH];       // packed entry per local slot (bucket-sorted)
    int tx = threadIdx.x;
    hA[tx] = 0; hB[tx] = 0;
    __syncthreads();

    int e0 = blockIdx.x * CH;
    int e1 = min(e0 + CH, E);
    int total = e1 - e0;

    for (int e = e0 + tx; e < e1; e += 512) {
        atomicAdd(&hA[dst[e] >> BSH], 1);
        atomicAdd(&hB[src[e] >> BSH], 1);
    }
    __syncthreads();

    // ================= side A (dst-keyed) =================
    {
        int v = hA[tx];
        sc[tx] = v;
        __syncthreads();
        for (int d = 1; d < 512; d <<= 1) {
            int t = (tx >= d) ? sc[tx - d] : 0;
            __syncthreads();
            sc[tx] += t;
            __syncthreads();
        }
        sc[tx] -= v;                                   // exclusive scan (local base)
        gb[tx] = v ? atomicAdd(&curA[tx], v) : 0;      // global base (bucket-relative)
        hA[tx] = 0;                                    // reuse as local cursor
        __syncthreads();
        for (int e = e0 + tx; e < e1; e += 512) {
            int s = src[e], d = dst[e];
            int k = d >> BSH;
            int pos = sc[k] + atomicAdd(&hA[k], 1);
            sent[pos] = ((uint_t)s << 8) | (uint_t)(d & 255);
            sbkt[pos] = (ushort_t)k;
        }
        __syncthreads();
        for (int p = tx; p < total; p += 512) {        // run-contiguous, coalesced
            int k = sbkt[p];
            int gp = gb[k] + (p - sc[k]);
            if (gp < CAP) binA[(size_t)k * CAP + gp] = sent[p];
        }
        __syncthreads();
    }

    // ================= side B (src-keyed) =================
    {
        int v = hB[tx];
        sc[tx] = v;
        __syncthreads();
        for (int d = 1; d < 512; d <<= 1) {
            int t = (tx >= d) ? sc[tx - d] : 0;
            __syncthreads();
            sc[tx] += t;
            __syncthreads();
        }
        sc[tx] -= v;
        gb[tx] = v ? atomicAdd(&curB[tx], v) : 0;
        hB[tx] = 0;
        __syncthreads();
        for (int e = e0 + tx; e < e1; e += 512) {
            int s = src[e], d = dst[e];
            int k = s >> BSH;
            int pos = sc[k] + atomicAdd(&hB[k], 1);
            sent[pos] = ((uint_t)d << 8) | (uint_t)(s & 255);
            sbkt[pos] = (ushort_t)k;
        }
        __syncthreads();
        for (int p = tx; p < total; p += 512) {
            int k = sbkt[p];
            int gp = gb[k] + (p - sc[p == p ? p : p]);   // (kept simple below)
            gp = gb[k] + (p - sc[k]);
            if (gp < CAP) binB[(size_t)k * CAP + gp] = sent[p];
        }
    }
}

// ---------------- per-bucket: degree + dinv + row ranges + CSR fill + padding ------
// R17: each node's segment is padded to a multiple of 16 with sentinel index N
// (zero row in the fp8 table) so agg8's loop is tail-free and branch-uniform.
__launch_bounds__(1024)
__global__ void k_csr(const uint_t* __restrict__ binA, const int* __restrict__ curA,
                      float* __restrict__ dinv, int* __restrict__ row_beg,
                      int* __restrict__ row_end, int* __restrict__ csr_src, int N) {
    __shared__ int hist[256];
    __shared__ int scan[256];
    int b = blockIdx.x;
    int tx = threadIdx.x;
    int cnt = min(curA[b], CAP);
    const uint_t* eb = binA + (size_t)b * CAP;

    if (tx < 256) hist[tx] = 0;
    __syncthreads();
    for (int e = tx; e < cnt; e += 1024)
        atomicAdd(&hist[eb[e] & 255u], 1);
    __syncthreads();
    int v = 0, pd = 0;
    if (tx < 256) {
        v = hist[tx];
        pd = (v + 15) & ~15;             // padded segment length
        scan[tx] = pd;
    }
    __syncthreads();
    for (int dd = 1; dd < 256; dd <<= 1) {
        int t = 0;
        if (tx < 256 && tx >= dd) t = scan[tx - dd];
        __syncthreads();
        if (tx < 256) scan[tx] += t;
        __syncthreads();
    }
    if (tx < 256) {
        int my_excl = scan[tx] - pd;
        int node = b * 256 + tx;
        if (node < N) {
            dinv[node] = rsqrtf((float)(v + 1));        // +1 self-loop (actual deg)
            row_beg[node] = b * CAP + my_excl;
            row_end[node] = b * CAP + my_excl + pd;     // padded length
        }
        // sentinel pads (disjoint from fill range [my_excl, my_excl+v))
        for (int i = v; i < pd; i++)
            csr_src[b * CAP + my_excl + i] = N;
        hist[tx] = my_excl;                              // reuse as fill cursor
    }
    __syncthreads();
    for (int e = tx; e < cnt; e += 1024) {
        uint_t pk = eb[e];
        int pos = b * CAP + atomicAdd(&hist[pk & 255u], 1);
        csr_src[pos] = (int)(pk >> 8);
    }
}

// ---------------- weight pack + bias permute + zero-row init (one launch) ---------
__global__ void k_wpack(const float* __restrict__ W1, const float* __restrict__ W2,
                        ushort_t* __restrict__ h1, ushort_t* __restrict__ l1,
                        ushort_t* __restrict__ h2, ushort_t* __restrict__ l2,
                        const float* __restrict__ b1, const float* __restrict__ b2,
                        float* __restrict__ bp1, float* __restrict__ bp2,
                        uint_t* __restrict__ zrow) {
    if (blockIdx.x == 128) {
        int p = threadIdx.x;
        if (p < 128) {
            int c = (p & 7) * 16 + (p >> 3);
            bp1[p] = b1[c];
            bp2[p] = b2[c];
        }
        if (p >= 128 && p < 160) zrow[p - 128] = 0;   // fp8 table sentinel row N
        return;
    }
    int gid = blockIdx.x * 256 + threadIdx.x;      // 0..32767
    int which = gid >> 14;
    int idx = gid & 16383;
    int k = idx >> 7, n = idx & 127;
    float w = which ? W2[(((k & 7) * 16) + (k >> 3)) * 128 + n] : W1[idx];
    ushort_t h = f2bf(w);
    ushort_t l = f2bf(w - bf2f(h));                // residual, makes W effectively fp32
    int c = k >> 5, quad = (k >> 3) & 3, jj = k & 7;
    int j = n >> 4, l16 = n & 15;
    int lane = quad * 16 + l16;
    int dest = ((c * 8 + j) * 64 + lane) * 8 + jj;
    if (which) { h2[dest] = h; l2[dest] = l; }
    else       { h1[dest] = h; l1[dest] = l; }
}

// ---------------- MFMA GEMM, fused scale+fp8 epilogue (permuted, coalesced) -------
template <int IN_F32>
__launch_bounds__(256)
__global__ void gemm_mfma(const void* __restrict__ Av, const ushort_t* __restrict__ Whi,
                          const ushort_t* __restrict__ Wlo, const float* __restrict__ dinv,
                          uchar_t* __restrict__ C8, int nrows) {
    int wave = threadIdx.x >> 6;
    int lane = threadIdx.x & 63;
    int quad = lane >> 4, l16 = lane & 15;
    int base = blockIdx.x * 128 + wave * 32;

    frag_cd acc[2][8];
#pragma unroll
    for (int rt = 0; rt < 2; rt++)
#pragma unroll
        for (int j = 0; j < 8; j++) acc[rt][j] = (frag_cd)0.f;

    const ushort_t* Ab = (const ushort_t*)Av;
    const float* Af = (const float*)Av;

#pragma unroll
    for (int c = 0; c < 4; c++) {
        frag_ab afrag[2];
        int koff = c * 32 + quad * 8;
#pragma unroll
        for (int rt = 0; rt < 2; rt++) {
            int row = min(base + rt * 16 + l16, nrows - 1);
            if (IN_F32) {
                const float* ap = Af + (size_t)row * D + koff;
                float4 a0 = *(const float4*)ap;
                float4 a1 = *(const float4*)(ap + 4);
                frag_u fu;
                fu.u[0] = f2bf(a0.x); fu.u[1] = f2bf(a0.y);
                fu.u[2] = f2bf(a0.z); fu.u[3] = f2bf(a0.w);
                fu.u[4] = f2bf(a1.x); fu.u[5] = f2bf(a1.y);
                fu.u[6] = f2bf(a1.z); fu.u[7] = f2bf(a1.w);
                afrag[rt] = fu.v;
            } else {
                afrag[rt] = *(const frag_ab*)(Ab + (size_t)row * D + koff);
            }
        }
#pragma unroll
        for (int j = 0; j < 8; j++) {
            frag_ab bh = *(const frag_ab*)(Whi + (((c * 8 + j) * 64 + lane) * 8));
            frag_ab bl = *(const frag_ab*)(Wlo + (((c * 8 + j) * 64 + lane) * 8));
#pragma unroll
            for (int rt = 0; rt < 2; rt++) {
                acc[rt][j] = __builtin_amdgcn_mfma_f32_16x16x32_bf16(afrag[rt], bh,
                                                                     acc[rt][j], 0, 0, 0);
                acc[rt][j] = __builtin_amdgcn_mfma_f32_16x16x32_bf16(afrag[rt], bl,
                                                                     acc[rt][j], 0, 0, 0);
            }
        }
    }

#pragma unroll
    for (int rt = 0; rt < 2; rt++) {
        int rbase = base + rt * 16 + quad * 4;
#pragma unroll
        for (int reg = 0; reg < 4; reg++) {
            int row = rbase + reg;
            if (row < nrows) {
                float dv = dinv[row];
                uint_t d0 = (uint_t)__builtin_amdgcn_cvt_pk_fp8_f32(
                    acc[rt][0][reg] * dv, acc[rt][1][reg] * dv, 0, false);
                d0 = (uint_t)__builtin_amdgcn_cvt_pk_fp8_f32(
                    acc[rt][2][reg] * dv, acc[rt][3][reg] * dv, (int)d0, true);
                uint_t d1 = (uint_t)__builtin_amdgcn_cvt_pk_fp8_f32(
                    acc[rt][4][reg] * dv, acc[rt][5][reg] * dv, 0, false);
                d1 = (uint_t)__builtin_amdgcn_cvt_pk_fp8_f32(
                    acc[rt][6][reg] * dv, acc[rt][7][reg] * dv, (int)d1, true);
                uint2 o; o.x = d0; o.y = d1;
                *(uint2*)(C8 + (size_t)row * D + l16 * 8) = o;
            }
        }
    }
}

// ---------------- aggregation (pre-scaled fp8 gather, pure sum, bf16 out) ----------
// out[n][p] = relu?( dn * ( u[n][p] + sum_e u[src][p] ) + bias[p] )
// R14 shape: one wave per node, 2 half-wave streams, depth-8 dword gathers,
// 32-bit saddr addressing, csr prefetch. R17: CSR segments are pre-padded to x16
// with sentinel row N (zeros) -> cnt%16==0, both halves have IDENTICAL nfull,
// no tail path, no clamps, fully uniform control flow.
__launch_bounds__(256)
__global__ void agg8(const uint_t* __restrict__ t8, const int* __restrict__ csr_src,
                     const int* __restrict__ row_beg, const int* __restrict__ row_end,
                     const float* __restrict__ dinv, const float* __restrict__ bias,
                     uint_t* __restrict__ out, int n, int do_relu) {
    int node = blockIdx.x * 4 + (threadIdx.x >> 6);
    if (node >= n) return;
    int lane = threadIdx.x & 63;
    int eh = lane >> 5;
    uint_t cl = (uint_t)(lane & 31);
    uint_t cl4 = cl * 4u;

    int beg = row_beg[node];
    int cnt = row_end[node] - beg;     // padded, multiple of 16
    float dn = dinv[node];

    float2v accA = {0.f, 0.f}, accB = {0.f, 0.f};

    if (eh == 0) {   // self term: table already holds dinv[n]*t[n]
        uint_t w = g8(t8, (uint_t)node * 128u + cl4);
        accA = __builtin_amdgcn_cvt_pk_f32_fp8(w, false);
        accB = __builtin_amdgcn_cvt_pk_f32_fp8(w, true);
    }

    int half = cnt >> 1;               // multiple of 8, same for both halves
    int e     = beg + (eh ? half : 0);
    int nfull = half >> 3;             // uniform across the wave

    uint4 sa, sb;
    if (nfull > 0) {
        __builtin_memcpy(&sa, csr_src + e, 16);        // 4B-aligned 16B loads
        __builtin_memcpy(&sb, csr_src + e + 4, 16);
    }
    for (int it = 0; it < nfull; ++it) {
        uint4 ca = sa, cb = sb;
        e += 8;
        if (it + 1 < nfull) {               // prefetch next batch's indices early
            __builtin_memcpy(&sa, csr_src + e, 16);
            __builtin_memcpy(&sb, csr_src + e + 4, 16);
        }
        uint_t w0 = g8(t8, ca.x * 128u + cl4);
        uint_t w1 = g8(t8, ca.y * 128u + cl4);
        uint_t w2 = g8(t8, ca.z * 128u + cl4);
        uint_t w3 = g8(t8, ca.w * 128u + cl4);
        uint_t w4 = g8(t8, cb.x * 128u + cl4);
        uint_t w5 = g8(t8, cb.y * 128u + cl4);
        uint_t w6 = g8(t8, cb.z * 128u + cl4);
        uint_t w7 = g8(t8, cb.w * 128u + cl4);
        acc_fp8(w0, accA, accB);
        acc_fp8(w1, accA, accB);
        acc_fp8(w2, accA, accB);
        acc_fp8(w3, accA, accB);
        acc_fp8(w4, accA, accB);
        acc_fp8(w5, accA, accB);
        acc_fp8(w6, accA, accB);
        acc_fp8(w7, accA, accB);
    }

    float a0 = accA.x, a1 = accA.y, a2 = accB.x, a3 = accB.y;
    a0 += __shfl(a0, lane ^ 32, 64);
    a1 += __shfl(a1, lane ^ 32, 64);
    a2 += __shfl(a2, lane ^ 32, 64);
    a3 += __shfl(a3, lane ^ 32, 64);

    if (eh == 0) {
        float4 bb = ((const float4*)bias)[cl];
        float o0 = dn * a0 + bb.x;
        float o1 = dn * a1 + bb.y;
        float o2 = dn * a2 + bb.z;
        float o3 = dn * a3 + bb.w;
        if (do_relu) {
            o0 = fmaxf(o0, 0.f); o1 = fmaxf(o1, 0.f);
            o2 = fmaxf(o2, 0.f); o3 = fmaxf(o3, 0.f);
        }
        uint2 ow;
        ow.x = (uint_t)f2bf(o0) | ((uint_t)f2bf(o1) << 16);
        ow.y = (uint_t)f2bf(o2) | ((uint_t)f2bf(o3) << 16);
        ((uint2*)out)[(size_t)node * 32 + cl] = ow;
    }
}

// ---------------- fused ow + weighted reduce (one block per 256-node bucket) -------
__launch_bounds__(512)
__global__ void wreduce(const ushort_t* __restrict__ h, const uint_t* __restrict__ binB,
                        const int* __restrict__ curB, const float* __restrict__ dinv,
                        float* __restrict__ v, int n) {
    __shared__ float owacc[256];
    __shared__ float s[512];
    int b = blockIdx.x;
    int tx = threadIdx.x;
    if (tx < 256) owacc[tx] = 0.f;
    __syncthreads();
    int cnt = min(curB[b], CAP);
    const uint_t* eb = binB + (size_t)b * CAP;
    for (int e = tx; e < cnt; e += 512) {
        uint_t pk = eb[e];
        atomicAdd(&owacc[pk & 255u], dinv[pk >> 8]);
    }
    __syncthreads();

    int c = tx & 127;
    int rg = tx >> 7;                    // 0..3
    int base = b * 256;
    int lim = min(base + 256, n);
    float acc = 0.f;
    for (int r = base + rg; r < lim; r += 4) {
        float dv = dinv[r];
        float cv = dv * (dv + owacc[r - base]);
        acc += cv * bf2f(h[(size_t)r * D + c]);
    }
    s[tx] = acc;
    __syncthreads();
    if (tx < 128)
        atomicAdd(&v[c], (s[tx] + s[tx + 128]) + (s[tx + 256] + s[tx + 384]));
}

// ---------------- finalize: out[j] = (v @ w3)[j]/N + b3[j], v is permuted ----------
__global__ void finalize(const float* __restrict__ v, const float* __restrict__ w3,
                         const float* __restrict__ b3, float* __restrict__ out, float invn) {
    __shared__ float sv[D];
    int j = threadIdx.x;
    sv[j] = v[j];
    __syncthreads();
    float acc = 0.f;
    for (int k = 0; k < D; k++) {
        int p = (k & 15) * 8 + (k >> 4);    // position of original channel k
        acc += sv[p] * w3[(size_t)k * D + j];
    }
    out[j] = acc * invn + b3[j];
}

extern "C" void kernel_launch(void* const* d_in, const int* in_sizes, int n_in,
                              void* d_out, int out_size, void* d_ws, size_t ws_size,
                              hipStream_t stream) {
    const float* x   = (const float*)d_in[0];
    const int*   ei  = (const int*)d_in[1];
    const float* w1  = (const float*)d_in[2];
    const float* b1  = (const float*)d_in[3];
    const float* w2  = (const float*)d_in[4];
    const float* b2  = (const float*)d_in[5];
    const float* w3  = (const float*)d_in[6];
    const float* b3  = (const float*)d_in[7];
    float* out = (float*)d_out;

    const int N = in_sizes[0] / D;       // 100000
    const int E = in_sizes[1] / 2;       // 3200000
    const int* src = ei;
    const int* dst = ei + E;
    const int nb = (N + 255) >> 8;       // 391 buckets of 256 nodes

    // ---- workspace layout ----
    char* p = (char*)d_ws;
    auto alloc = [&](size_t bytes) -> char* {
        char* r = p;
        p += (bytes + 255) & ~(size_t)255;
        return r;
    };
    char*     zbeg     = p;
    int*      curA     = (int*)alloc(512 * 4);
    int*      curB     = (int*)alloc(512 * 4);
    float*    v        = (float*)alloc((size_t)D * 4);
    char*     zend     = p;
    float*    dinv     = (float*)alloc((size_t)N * 4);
    int*      row_beg  = (int*)alloc((size_t)N * 4);
    int*      row_end  = (int*)alloc((size_t)N * 4);
    ushort_t* wp1h     = (ushort_t*)alloc(16384 * 2);
    ushort_t* wp1l     = (ushort_t*)alloc(16384 * 2);
    ushort_t* wp2h     = (ushort_t*)alloc(16384 * 2);
    ushort_t* wp2l     = (ushort_t*)alloc(16384 * 2);
    float*    bp1      = (float*)alloc(D * 4);
    float*    bp2      = (float*)alloc(D * 4);
    uint_t*   binA     = (uint_t*)alloc((size_t)nb * CAP * 4);  // 19.2 MB
    uint_t*   binB     = (uint_t*)alloc((size_t)nb * CAP * 4);  // 19.2 MB
    int*      csr_src  = (int*)alloc((size_t)nb * CAP * 4);     // 19.2 MB
    ushort_t* bufH     = (ushort_t*)alloc((size_t)N * D * 2);   // bf16 agg out
    uint_t*   buf8     = (uint_t*)alloc((size_t)(N + 1) * 32 * 4); // fp8 table + zero row
    (void)ws_size;

    const int gG = (N + 127) / 128;      // MFMA gemm grid

    // zero curA/curB/v
    hipMemsetAsync(zbeg, 0, (size_t)(zend - zbeg), stream);

    // weight packing + bias permute + table zero-row init (single launch)
    k_wpack<<<129, 256, 0, stream>>>(w1, w2, wp1h, wp1l, wp2h, wp2l, b1, b2, bp1, bp2,
                                     buf8 + (size_t)N * 32);

    // graph preprocessing: bin edges (4B entries), then per-bucket degree/CSR+pad
    k_bin<<<(E + CH - 1) / CH, 512, 0, stream>>>(src, dst, curA, curB, binA, binB, E, nb);
    k_csr<<<nb, 1024, 0, stream>>>(binA, curA, dinv, row_beg, row_end, csr_src, N);

    // layer 1: u1 = fp8(dinv * (x@w1)) permuted ; h1 = relu(dn*(sum u1)+b1) (bf16)
    gemm_mfma<1><<<gG, 256, 0, stream>>>(x, wp1h, wp1l, dinv, (uchar_t*)buf8, N);
    agg8<<<(N + 3) / 4, 256, 0, stream>>>(buf8, csr_src, row_beg, row_end, dinv, bp1,
                                          (uint_t*)bufH, N, 1);
    // layer 2 (A permuted, W2 rows permuted to match)
    gemm_mfma<0><<<gG, 256, 0, stream>>>(bufH, wp2h, wp2l, dinv, (uchar_t*)buf8, N);
    agg8<<<(N + 3) / 4, 256, 0, stream>>>(buf8, csr_src, row_beg, row_end, dinv, bp2,
                                          (uint_t*)bufH, N, 1);
    // layer 3 collapsed: v = sum_i cvec[i]*h2[i] (ow fused in) ; out = v@w3/N + b3
    wreduce<<<nb, 512, 0, stream>>>(bufH, binB, curB, dinv, v, N);
    finalize<<<1, D, 0, stream>>>(v, w3, b3, out, 1.0f / (float)N);
}

// Round 7
// 365.559 us; speedup vs baseline: 1.1863x; 1.0331x over previous
//
#include <hip/hip_runtime.h>

#define D 128
#define BSH 8          // 256 nodes per bucket
#define CAP 12288      // slots per bucket (R17: raised from 10240 for CSR padding;
                       // padded bucket total mean ~10.1K, sigma ~116 -> 18 sigma)
#define CH 8192        // edges per k_bin block (512 threads, 391 blocks)
                       // CH=4096 regressed (spans ~42B -> partial-line write amp 6x);
                       // CH=8192 spans ~84B, all CUs covered. [R10/R11 post-mortem]
                       // R12 FAILED: per-edge global fp32 atomics for ow[] ~100us.
                       // R13 WIN: LDS bucket-sort + coalesced copy-out, 428 -> 400us.
                       // R14 WIN: agg8 saddr gathers + csr prefetch + masked tail,
                       // 400 -> 377us (agg8 56.3us each).
                       // R15 FAILED (80us): quarter-wave split; per-node fixed costs
                       // dominate at mean deg 32 — don't shrink stream grain.
                       // R16 FAILED (87us): depth 16; VGPR 52 + 20 VMEM in flight
                       // crossed a resource cliff (occ 71->37%) + heavier tail.
                       // R17 NEUTRAL: tail-free padded CSR; agg8 56.3->54.9 only ->
                       // agg8 ~55us is the structural floor of the gather layout
                       // (VALU 57 / HBM 44 / occ 73, no idle pipe). Shelved.
                       // R18: k_bin edge cache in REGISTERS (16 edges/thread) —
                       // edges read from HBM once instead of 3x (77 -> 26 MB).

typedef unsigned short ushort_t;
typedef unsigned int uint_t;
typedef unsigned char uchar_t;

typedef __attribute__((ext_vector_type(8))) short frag_ab;   // 8 bf16 (4 VGPRs)
typedef __attribute__((ext_vector_type(4))) float frag_cd;   // 4 fp32 acc
typedef __attribute__((ext_vector_type(2))) float float2v;

union frag_u { ushort_t u[8]; frag_ab v; };

// Channel permutation: MFMA C-col c = j*16+l16 stored at position p = (c&15)*8 + (c>>4).
// Inverse: c = (p&7)*16 + (p>>3). Elementwise stages use positions; W2 rows and the
// finalize w3 contraction are permuted to match.

__device__ __forceinline__ float bf2f(ushort_t u) {
    union { uint_t i; float f; } v; v.i = ((uint_t)u) << 16; return v.f;
}
__device__ __forceinline__ ushort_t f2bf(float f) {
    union { float f; uint_t i; } v; v.f = f;
    uint_t u = v.i;
    u += 0x7fffu + ((u >> 16) & 1u);   // round-to-nearest-even
    return (ushort_t)(u >> 16);
}

// fp8 accumulate helpers (agg8)
__device__ __forceinline__ void acc_fp8(uint_t w, float2v& aA, float2v& aB) {
    aA += __builtin_amdgcn_cvt_pk_f32_fp8(w, false);
    aB += __builtin_amdgcn_cvt_pk_f32_fp8(w, true);
}
// gather with explicit 32-bit BYTE offset -> compiler emits saddr+voffset form
// (1 v_lshl_add_u32 per gather instead of 64-bit address arith). [R14]
__device__ __forceinline__ uint_t g8(const uint_t* __restrict__ t8, uint_t byteoff) {
    return *(const uint_t*)((const char*)t8 + byteoff);
}

// ---------------- edge binning into 256-node buckets, 4B packed entries ----------
// binA (dst-keyed): (src<<8) | (dst&255).  binB (src-keyed): (dst<<8) | (src&255).
// R13: entries are bucket-sorted in LDS (local scan + cursor), then copied out as
// contiguous runs so global writes coalesce into full lines.
// R18: the block's 8192 edges are cached in REGISTERS (16/thread, statically
// indexed full unroll) during the histogram pass; both fill passes consume the
// registers -> src/dst arrays are read from global exactly once.
__launch_bounds__(512)
__global__ void k_bin(const int* __restrict__ src, const int* __restrict__ dst,
                      int* __restrict__ curA, int* __restrict__ curB,
                      uint_t* __restrict__ binA, uint_t* __restrict__ binB,
                      int E, int nb) {
    __shared__ int hA[512], hB[512], sc[512], gb[512];
    __shared__ ushort_t sbkt[CH];     // bucket id per local slot
    __shared__ uint_t sent[CH];       // packed entry per local slot (bucket-sorted)
    int tx = threadIdx.x;
    hA[tx] = 0; hB[tx] = 0;
    __syncthreads();

    int e0 = blockIdx.x * CH;
    int e1 = min(e0 + CH, E);
    int total = e1 - e0;

    // load edges into registers + histogram both sides (single global read)
    int sreg[16], dreg[16];
#pragma unroll
    for (int it = 0; it < 16; ++it) {
        int e = e0 + tx + it * 512;
        if (e < e1) {
            int s = src[e], d = dst[e];
            sreg[it] = s; dreg[it] = d;
            atomicAdd(&hA[d >> BSH], 1);
            atomicAdd(&hB[s >> BSH], 1);
        }
    }
    __syncthreads();

    // ================= side A (dst-keyed) =================
    {
        int v = hA[tx];
        sc[tx] = v;
        __syncthreads();
        for (int d = 1; d < 512; d <<= 1) {
            int t = (tx >= d) ? sc[tx - d] : 0;
            __syncthreads();
            sc[tx] += t;
            __syncthreads();
        }
        sc[tx] -= v;                                   // exclusive scan (local base)
        gb[tx] = v ? atomicAdd(&curA[tx], v) : 0;      // global base (bucket-relative)
        hA[tx] = 0;                                    // reuse as local cursor
        __syncthreads();
#pragma unroll
        for (int it = 0; it < 16; ++it) {
            int e = e0 + tx + it * 512;
            if (e < e1) {
                int s = sreg[it], d = dreg[it];
                int k = d >> BSH;
                int pos = sc[k] + atomicAdd(&hA[k], 1);
                sent[pos] = ((uint_t)s << 8) | (uint_t)(d & 255);
                sbkt[pos] = (ushort_t)k;
            }
        }
        __syncthreads();
        for (int p = tx; p < total; p += 512) {        // run-contiguous, coalesced
            int k = sbkt[p];
            int gp = gb[k] + (p - sc[k]);
            if (gp < CAP) binA[(size_t)k * CAP + gp] = sent[p];
        }
        __syncthreads();
    }

    // ================= side B (src-keyed) =================
    {
        int v = hB[tx];
        sc[tx] = v;
        __syncthreads();
        for (int d = 1; d < 512; d <<= 1) {
            int t = (tx >= d) ? sc[tx - d] : 0;
            __syncthreads();
            sc[tx] += t;
            __syncthreads();
        }
        sc[tx] -= v;
        gb[tx] = v ? atomicAdd(&curB[tx], v) : 0;
        hB[tx] = 0;
        __syncthreads();
#pragma unroll
        for (int it = 0; it < 16; ++it) {
            int e = e0 + tx + it * 512;
            if (e < e1) {
                int s = sreg[it], d = dreg[it];
                int k = s >> BSH;
                int pos = sc[k] + atomicAdd(&hB[k], 1);
                sent[pos] = ((uint_t)d << 8) | (uint_t)(s & 255);
                sbkt[pos] = (ushort_t)k;
            }
        }
        __syncthreads();
        for (int p = tx; p < total; p += 512) {
            int k = sbkt[p];
            int gp = gb[k] + (p - sc[k]);
            if (gp < CAP) binB[(size_t)k * CAP + gp] = sent[p];
        }
    }
}

// ---------------- per-bucket: degree + dinv + row ranges + CSR fill + padding ------
// R17: each node's segment is padded to a multiple of 16 with sentinel index N
// (zero row in the fp8 table) so agg8's loop is tail-free and branch-uniform.
__launch_bounds__(1024)
__global__ void k_csr(const uint_t* __restrict__ binA, const int* __restrict__ curA,
                      float* __restrict__ dinv, int* __restrict__ row_beg,
                      int* __restrict__ row_end, int* __restrict__ csr_src, int N) {
    __shared__ int hist[256];
    __shared__ int scan[256];
    int b = blockIdx.x;
    int tx = threadIdx.x;
    int cnt = min(curA[b], CAP);
    const uint_t* eb = binA + (size_t)b * CAP;

    if (tx < 256) hist[tx] = 0;
    __syncthreads();
    for (int e = tx; e < cnt; e += 1024)
        atomicAdd(&hist[eb[e] & 255u], 1);
    __syncthreads();
    int v = 0, pd = 0;
    if (tx < 256) {
        v = hist[tx];
        pd = (v + 15) & ~15;             // padded segment length
        scan[tx] = pd;
    }
    __syncthreads();
    for (int dd = 1; dd < 256; dd <<= 1) {
        int t = 0;
        if (tx < 256 && tx >= dd) t = scan[tx - dd];
        __syncthreads();
        if (tx < 256) scan[tx] += t;
        __syncthreads();
    }
    if (tx < 256) {
        int my_excl = scan[tx] - pd;
        int node = b * 256 + tx;
        if (node < N) {
            dinv[node] = rsqrtf((float)(v + 1));        // +1 self-loop (actual deg)
            row_beg[node] = b * CAP + my_excl;
            row_end[node] = b * CAP + my_excl + pd;     // padded length
        }
        // sentinel pads (disjoint from fill range [my_excl, my_excl+v))
        for (int i = v; i < pd; i++)
            csr_src[b * CAP + my_excl + i] = N;
        hist[tx] = my_excl;                              // reuse as fill cursor
    }
    __syncthreads();
    for (int e = tx; e < cnt; e += 1024) {
        uint_t pk = eb[e];
        int pos = b * CAP + atomicAdd(&hist[pk & 255u], 1);
        csr_src[pos] = (int)(pk >> 8);
    }
}

// ---------------- weight pack + bias permute + zero-row init (one launch) ---------
__global__ void k_wpack(const float* __restrict__ W1, const float* __restrict__ W2,
                        ushort_t* __restrict__ h1, ushort_t* __restrict__ l1,
                        ushort_t* __restrict__ h2, ushort_t* __restrict__ l2,
                        const float* __restrict__ b1, const float* __restrict__ b2,
                        float* __restrict__ bp1, float* __restrict__ bp2,
                        uint_t* __restrict__ zrow) {
    if (blockIdx.x == 128) {
        int p = threadIdx.x;
        if (p < 128) {
            int c = (p & 7) * 16 + (p >> 3);
            bp1[p] = b1[c];
            bp2[p] = b2[c];
        }
        if (p >= 128 && p < 160) zrow[p - 128] = 0;   // fp8 table sentinel row N
        return;
    }
    int gid = blockIdx.x * 256 + threadIdx.x;      // 0..32767
    int which = gid >> 14;
    int idx = gid & 16383;
    int k = idx >> 7, n = idx & 127;
    float w = which ? W2[(((k & 7) * 16) + (k >> 3)) * 128 + n] : W1[idx];
    ushort_t h = f2bf(w);
    ushort_t l = f2bf(w - bf2f(h));                // residual, makes W effectively fp32
    int c = k >> 5, quad = (k >> 3) & 3, jj = k & 7;
    int j = n >> 4, l16 = n & 15;
    int lane = quad * 16 + l16;
    int dest = ((c * 8 + j) * 64 + lane) * 8 + jj;
    if (which) { h2[dest] = h; l2[dest] = l; }
    else       { h1[dest] = h; l1[dest] = l; }
}

// ---------------- MFMA GEMM, fused scale+fp8 epilogue (permuted, coalesced) -------
template <int IN_F32>
__launch_bounds__(256)
__global__ void gemm_mfma(const void* __restrict__ Av, const ushort_t* __restrict__ Whi,
                          const ushort_t* __restrict__ Wlo, const float* __restrict__ dinv,
                          uchar_t* __restrict__ C8, int nrows) {
    int wave = threadIdx.x >> 6;
    int lane = threadIdx.x & 63;
    int quad = lane >> 4, l16 = lane & 15;
    int base = blockIdx.x * 128 + wave * 32;

    frag_cd acc[2][8];
#pragma unroll
    for (int rt = 0; rt < 2; rt++)
#pragma unroll
        for (int j = 0; j < 8; j++) acc[rt][j] = (frag_cd)0.f;

    const ushort_t* Ab = (const ushort_t*)Av;
    const float* Af = (const float*)Av;

#pragma unroll
    for (int c = 0; c < 4; c++) {
        frag_ab afrag[2];
        int koff = c * 32 + quad * 8;
#pragma unroll
        for (int rt = 0; rt < 2; rt++) {
            int row = min(base + rt * 16 + l16, nrows - 1);
            if (IN_F32) {
                const float* ap = Af + (size_t)row * D + koff;
                float4 a0 = *(const float4*)ap;
                float4 a1 = *(const float4*)(ap + 4);
                frag_u fu;
                fu.u[0] = f2bf(a0.x); fu.u[1] = f2bf(a0.y);
                fu.u[2] = f2bf(a0.z); fu.u[3] = f2bf(a0.w);
                fu.u[4] = f2bf(a1.x); fu.u[5] = f2bf(a1.y);
                fu.u[6] = f2bf(a1.z); fu.u[7] = f2bf(a1.w);
                afrag[rt] = fu.v;
            } else {
                afrag[rt] = *(const frag_ab*)(Ab + (size_t)row * D + koff);
            }
        }
#pragma unroll
        for (int j = 0; j < 8; j++) {
            frag_ab bh = *(const frag_ab*)(Whi + (((c * 8 + j) * 64 + lane) * 8));
            frag_ab bl = *(const frag_ab*)(Wlo + (((c * 8 + j) * 64 + lane) * 8));
#pragma unroll
            for (int rt = 0; rt < 2; rt++) {
                acc[rt][j] = __builtin_amdgcn_mfma_f32_16x16x32_bf16(afrag[rt], bh,
                                                                     acc[rt][j], 0, 0, 0);
                acc[rt][j] = __builtin_amdgcn_mfma_f32_16x16x32_bf16(afrag[rt], bl,
                                                                     acc[rt][j], 0, 0, 0);
            }
        }
    }

#pragma unroll
    for (int rt = 0; rt < 2; rt++) {
        int rbase = base + rt * 16 + quad * 4;
#pragma unroll
        for (int reg = 0; reg < 4; reg++) {
            int row = rbase + reg;
            if (row < nrows) {
                float dv = dinv[row];
                uint_t d0 = (uint_t)__builtin_amdgcn_cvt_pk_fp8_f32(
                    acc[rt][0][reg] * dv, acc[rt][1][reg] * dv, 0, false);
                d0 = (uint_t)__builtin_amdgcn_cvt_pk_fp8_f32(
                    acc[rt][2][reg] * dv, acc[rt][3][reg] * dv, (int)d0, true);
                uint_t d1 = (uint_t)__builtin_amdgcn_cvt_pk_fp8_f32(
                    acc[rt][4][reg] * dv, acc[rt][5][reg] * dv, 0, false);
                d1 = (uint_t)__builtin_amdgcn_cvt_pk_fp8_f32(
                    acc[rt][6][reg] * dv, acc[rt][7][reg] * dv, (int)d1, true);
                uint2 o; o.x = d0; o.y = d1;
                *(uint2*)(C8 + (size_t)row * D + l16 * 8) = o;
            }
        }
    }
}

// ---------------- aggregation (pre-scaled fp8 gather, pure sum, bf16 out) ----------
// out[n][p] = relu?( dn * ( u[n][p] + sum_e u[src][p] ) + bias[p] )
// R14 shape: one wave per node, 2 half-wave streams, depth-8 dword gathers,
// 32-bit saddr addressing, csr prefetch. R17: CSR segments are pre-padded to x16
// with sentinel row N (zeros) -> cnt%16==0, both halves have IDENTICAL nfull,
// no tail path, no clamps, fully uniform control flow. ~55us structural floor.
__launch_bounds__(256)
__global__ void agg8(const uint_t* __restrict__ t8, const int* __restrict__ csr_src,
                     const int* __restrict__ row_beg, const int* __restrict__ row_end,
                     const float* __restrict__ dinv, const float* __restrict__ bias,
                     uint_t* __restrict__ out, int n, int do_relu) {
    int node = blockIdx.x * 4 + (threadIdx.x >> 6);
    if (node >= n) return;
    int lane = threadIdx.x & 63;
    int eh = lane >> 5;
    uint_t cl = (uint_t)(lane & 31);
    uint_t cl4 = cl * 4u;

    int beg = row_beg[node];
    int cnt = row_end[node] - beg;     // padded, multiple of 16
    float dn = dinv[node];

    float2v accA = {0.f, 0.f}, accB = {0.f, 0.f};

    if (eh == 0) {   // self term: table already holds dinv[n]*t[n]
        uint_t w = g8(t8, (uint_t)node * 128u + cl4);
        accA = __builtin_amdgcn_cvt_pk_f32_fp8(w, false);
        accB = __builtin_amdgcn_cvt_pk_f32_fp8(w, true);
    }

    int half = cnt >> 1;               // multiple of 8, same for both halves
    int e     = beg + (eh ? half : 0);
    int nfull = half >> 3;             // uniform across the wave

    uint4 sa, sb;
    if (nfull > 0) {
        __builtin_memcpy(&sa, csr_src + e, 16);        // 4B-aligned 16B loads
        __builtin_memcpy(&sb, csr_src + e + 4, 16);
    }
    for (int it = 0; it < nfull; ++it) {
        uint4 ca = sa, cb = sb;
        e += 8;
        if (it + 1 < nfull) {               // prefetch next batch's indices early
            __builtin_memcpy(&sa, csr_src + e, 16);
            __builtin_memcpy(&sb, csr_src + e + 4, 16);
        }
        uint_t w0 = g8(t8, ca.x * 128u + cl4);
        uint_t w1 = g8(t8, ca.y * 128u + cl4);
        uint_t w2 = g8(t8, ca.z * 128u + cl4);
        uint_t w3 = g8(t8, ca.w * 128u + cl4);
        uint_t w4 = g8(t8, cb.x * 128u + cl4);
        uint_t w5 = g8(t8, cb.y * 128u + cl4);
        uint_t w6 = g8(t8, cb.z * 128u + cl4);
        uint_t w7 = g8(t8, cb.w * 128u + cl4);
        acc_fp8(w0, accA, accB);
        acc_fp8(w1, accA, accB);
        acc_fp8(w2, accA, accB);
        acc_fp8(w3, accA, accB);
        acc_fp8(w4, accA, accB);
        acc_fp8(w5, accA, accB);
        acc_fp8(w6, accA, accB);
        acc_fp8(w7, accA, accB);
    }

    float a0 = accA.x, a1 = accA.y, a2 = accB.x, a3 = accB.y;
    a0 += __shfl(a0, lane ^ 32, 64);
    a1 += __shfl(a1, lane ^ 32, 64);
    a2 += __shfl(a2, lane ^ 32, 64);
    a3 += __shfl(a3, lane ^ 32, 64);

    if (eh == 0) {
        float4 bb = ((const float4*)bias)[cl];
        float o0 = dn * a0 + bb.x;
        float o1 = dn * a1 + bb.y;
        float o2 = dn * a2 + bb.z;
        float o3 = dn * a3 + bb.w;
        if (do_relu) {
            o0 = fmaxf(o0, 0.f); o1 = fmaxf(o1, 0.f);
            o2 = fmaxf(o2, 0.f); o3 = fmaxf(o3, 0.f);
        }
        uint2 ow;
        ow.x = (uint_t)f2bf(o0) | ((uint_t)f2bf(o1) << 16);
        ow.y = (uint_t)f2bf(o2) | ((uint_t)f2bf(o3) << 16);
        ((uint2*)out)[(size_t)node * 32 + cl] = ow;
    }
}

// ---------------- fused ow + weighted reduce (one block per 256-node bucket) -------
__launch_bounds__(512)
__global__ void wreduce(const ushort_t* __restrict__ h, const uint_t* __restrict__ binB,
                        const int* __restrict__ curB, const float* __restrict__ dinv,
                        float* __restrict__ v, int n) {
    __shared__ float owacc[256];
    __shared__ float s[512];
    int b = blockIdx.x;
    int tx = threadIdx.x;
    if (tx < 256) owacc[tx] = 0.f;
    __syncthreads();
    int cnt = min(curB[b], CAP);
    const uint_t* eb = binB + (size_t)b * CAP;
    for (int e = tx; e < cnt; e += 512) {
        uint_t pk = eb[e];
        atomicAdd(&owacc[pk & 255u], dinv[pk >> 8]);
    }
    __syncthreads();

    int c = tx & 127;
    int rg = tx >> 7;                    // 0..3
    int base = b * 256;
    int lim = min(base + 256, n);
    float acc = 0.f;
    for (int r = base + rg; r < lim; r += 4) {
        float dv = dinv[r];
        float cv = dv * (dv + owacc[r - base]);
        acc += cv * bf2f(h[(size_t)r * D + c]);
    }
    s[tx] = acc;
    __syncthreads();
    if (tx < 128)
        atomicAdd(&v[c], (s[tx] + s[tx + 128]) + (s[tx + 256] + s[tx + 384]));
}

// ---------------- finalize: out[j] = (v @ w3)[j]/N + b3[j], v is permuted ----------
__global__ void finalize(const float* __restrict__ v, const float* __restrict__ w3,
                         const float* __restrict__ b3, float* __restrict__ out, float invn) {
    __shared__ float sv[D];
    int j = threadIdx.x;
    sv[j] = v[j];
    __syncthreads();
    float acc = 0.f;
    for (int k = 0; k < D; k++) {
        int p = (k & 15) * 8 + (k >> 4);    // position of original channel k
        acc += sv[p] * w3[(size_t)k * D + j];
    }
    out[j] = acc * invn + b3[j];
}

extern "C" void kernel_launch(void* const* d_in, const int* in_sizes, int n_in,
                              void* d_out, int out_size, void* d_ws, size_t ws_size,
                              hipStream_t stream) {
    const float* x   = (const float*)d_in[0];
    const int*   ei  = (const int*)d_in[1];
    const float* w1  = (const float*)d_in[2];
    const float* b1  = (const float*)d_in[3];
    const float* w2  = (const float*)d_in[4];
    const float* b2  = (const float*)d_in[5];
    const float* w3  = (const float*)d_in[6];
    const float* b3  = (const float*)d_in[7];
    float* out = (float*)d_out;

    const int N = in_sizes[0] / D;       // 100000
    const int E = in_sizes[1] / 2;       // 3200000
    const int* src = ei;
    const int* dst = ei + E;
    const int nb = (N + 255) >> 8;       // 391 buckets of 256 nodes

    // ---- workspace layout ----
    char* p = (char*)d_ws;
    auto alloc = [&](size_t bytes) -> char* {
        char* r = p;
        p += (bytes + 255) & ~(size_t)255;
        return r;
    };
    char*     zbeg     = p;
    int*      curA     = (int*)alloc(512 * 4);
    int*      curB     = (int*)alloc(512 * 4);
    float*    v        = (float*)alloc((size_t)D * 4);
    char*     zend     = p;
    float*    dinv     = (float*)alloc((size_t)N * 4);
    int*      row_beg  = (int*)alloc((size_t)N * 4);
    int*      row_end  = (int*)alloc((size_t)N * 4);
    ushort_t* wp1h     = (ushort_t*)alloc(16384 * 2);
    ushort_t* wp1l     = (ushort_t*)alloc(16384 * 2);
    ushort_t* wp2h     = (ushort_t*)alloc(16384 * 2);
    ushort_t* wp2l     = (ushort_t*)alloc(16384 * 2);
    float*    bp1      = (float*)alloc(D * 4);
    float*    bp2      = (float*)alloc(D * 4);
    uint_t*   binA     = (uint_t*)alloc((size_t)nb * CAP * 4);  // 19.2 MB
    uint_t*   binB     = (uint_t*)alloc((size_t)nb * CAP * 4);  // 19.2 MB
    int*      csr_src  = (int*)alloc((size_t)nb * CAP * 4);     // 19.2 MB
    ushort_t* bufH     = (ushort_t*)alloc((size_t)N * D * 2);   // bf16 agg out
    uint_t*   buf8     = (uint_t*)alloc((size_t)(N + 1) * 32 * 4); // fp8 table + zero row
    (void)ws_size;

    const int gG = (N + 127) / 128;      // MFMA gemm grid

    // zero curA/curB/v
    hipMemsetAsync(zbeg, 0, (size_t)(zend - zbeg), stream);

    // weight packing + bias permute + table zero-row init (single launch)
    k_wpack<<<129, 256, 0, stream>>>(w1, w2, wp1h, wp1l, wp2h, wp2l, b1, b2, bp1, bp2,
                                     buf8 + (size_t)N * 32);

    // graph preprocessing: bin edges (4B entries), then per-bucket degree/CSR+pad
    k_bin<<<(E + CH - 1) / CH, 512, 0, stream>>>(src, dst, curA, curB, binA, binB, E, nb);
    k_csr<<<nb, 1024, 0, stream>>>(binA, curA, dinv, row_beg, row_end, csr_src, N);

    // layer 1: u1 = fp8(dinv * (x@w1)) permuted ; h1 = relu(dn*(sum u1)+b1) (bf16)
    gemm_mfma<1><<<gG, 256, 0, stream>>>(x, wp1h, wp1l, dinv, (uchar_t*)buf8, N);
    agg8<<<(N + 3) / 4, 256, 0, stream>>>(buf8, csr_src, row_beg, row_end, dinv, bp1,
                                          (uint_t*)bufH, N, 1);
    // layer 2 (A permuted, W2 rows permuted to match)
    gemm_mfma<0><<<gG, 256, 0, stream>>>(bufH, wp2h, wp2l, dinv, (uchar_t*)buf8, N);
    agg8<<<(N + 3) / 4, 256, 0, stream>>>(buf8, csr_src, row_beg, row_end, dinv, bp2,
                                          (uint_t*)bufH, N, 1);
    // layer 3 collapsed: v = sum_i cvec[i]*h2[i] (ow fused in) ; out = v@w3/N + b3
    wreduce<<<nb, 512, 0, stream>>>(bufH, binB, curB, dinv, v, N);
    finalize<<<1, D, 0, stream>>>(v, w3, b3, out, 1.0f / (float)N);
}